// Round 1
// baseline (1010.954 us; speedup 1.0000x reference)
//
#include <hip/hip_runtime.h>
#include <math.h>

#define NATOM 100000
#define MNBR 12
#define FDIM 128
#define NFDIM 64

// ---------------------------------------------------------------------------
// K1: fused QKV projection.  [N,128] @ (Wq|Wk|Wv) + bias -> q,k,v in ws.
// 32 atoms/block (weight reuse x32 across L2), 256 threads.
// thread = (col j = tid&127, half = tid>>7 handling 16 atoms each)
// ---------------------------------------------------------------------------
__global__ __launch_bounds__(256) void qkv_kernel(
    const float* __restrict__ atom_fea,
    const float* __restrict__ Wq, const float* __restrict__ bq,
    const float* __restrict__ Wk, const float* __restrict__ bk,
    const float* __restrict__ Wv, const float* __restrict__ bv,
    float* __restrict__ q, float* __restrict__ k, float* __restrict__ v)
{
    __shared__ float s_a[32 * 128];   // 16 KB
    const int tid = threadIdx.x;
    const long long base = (long long)blockIdx.x * (32 * 128);
#pragma unroll
    for (int t = 0; t < 16; ++t)
        s_a[tid + t * 256] = atom_fea[base + tid + t * 256];
    __syncthreads();

    const int j = tid & 127;
    const int half = tid >> 7;
    float aq[16], ak[16], av[16];
#pragma unroll
    for (int a = 0; a < 16; ++a) { aq[a] = 0.f; ak[a] = 0.f; av[a] = 0.f; }

    const float* srow = s_a + half * (16 * 128);
    for (int i = 0; i < 128; i += 4) {
        float wq[4], wk[4], wv[4];
#pragma unroll
        for (int ii = 0; ii < 4; ++ii) {
            wq[ii] = Wq[(i + ii) * 128 + j];
            wk[ii] = Wk[(i + ii) * 128 + j];
            wv[ii] = Wv[(i + ii) * 128 + j];
        }
#pragma unroll
        for (int a = 0; a < 16; ++a) {
            float4 x = *(const float4*)(srow + a * 128 + i);  // LDS broadcast
            aq[a] += x.x * wq[0] + x.y * wq[1] + x.z * wq[2] + x.w * wq[3];
            ak[a] += x.x * wk[0] + x.y * wk[1] + x.z * wk[2] + x.w * wk[3];
            av[a] += x.x * wv[0] + x.y * wv[1] + x.z * wv[2] + x.w * wv[3];
        }
    }
    const float bqj = bq[j], bkj = bk[j], bvj = bv[j];
#pragma unroll
    for (int a = 0; a < 16; ++a) {
        long long row = (long long)blockIdx.x * 32 + half * 16 + a;
        q[row * 128 + j] = aq[a] + bqj;
        k[row * 128 + j] = ak[a] + bkj;
        v[row * 128 + j] = av[a] + bvj;
    }
}

// ---------------------------------------------------------------------------
// K2: fused neighbor projection + gather + attention.
// 8 atoms/block, 32 threads/atom, 4 cols/thread (col = c*32 + t32).
// nbr_t never materialized. Scores via width-16 shuffle butterflies
// (head = 16 contiguous cols, aligned with shuffle groups).
// Writes att over the q buffer (q[n] only read by this block).
// ---------------------------------------------------------------------------
__global__ __launch_bounds__(256) void attn_kernel(
    const float* __restrict__ nbr_fea,
    const int*   __restrict__ nbr_idx,
    const float* __restrict__ Wn, const float* __restrict__ bn,
    float* qatt,                                  // q in, att out (aliased)
    const float* __restrict__ kbuf,
    const float* __restrict__ vbuf)
{
    __shared__ float s_nbr[8 * 768];  // 24 KB, [atom][m*64+i]
    const int tid = threadIdx.x;
    const long long blk = blockIdx.x;

    const float* gsrc = nbr_fea + blk * (8 * 768);
#pragma unroll
    for (int t = 0; t < 24; ++t)
        s_nbr[tid + t * 256] = gsrc[tid + t * 256];
    __syncthreads();

    const int t32 = tid & 31;
    const int al  = tid >> 5;                 // local atom 0..7
    const long long n = blk * 8 + al;         // global atom
    const float* snb = s_nbr + al * 768;

    float acc[4][12];                          // nbr_t partials -> later nv
#pragma unroll
    for (int c = 0; c < 4; ++c)
#pragma unroll
        for (int m = 0; m < 12; ++m) acc[c][m] = 0.f;

    for (int i = 0; i < 64; i += 4) {
        float w[4][4];                         // [ii][c]
#pragma unroll
        for (int ii = 0; ii < 4; ++ii)
#pragma unroll
            for (int c = 0; c < 4; ++c)
                w[ii][c] = Wn[(i + ii) * 128 + c * 32 + t32];
#pragma unroll
        for (int m = 0; m < 12; ++m) {
            float4 x = *(const float4*)(snb + m * 64 + i);  // 2-way bcast (free)
#pragma unroll
            for (int c = 0; c < 4; ++c)
                acc[c][m] += x.x * w[0][c] + x.y * w[1][c]
                           + x.z * w[2][c] + x.w * w[3][c];
        }
    }

    int nofs[12];
#pragma unroll
    for (int m = 0; m < 12; ++m) nofs[m] = nbr_idx[n * 12 + m];

    float qv[4], bnv[4];
#pragma unroll
    for (int c = 0; c < 4; ++c) {
        qv[c]  = qatt[n * 128 + c * 32 + t32];
        bnv[c] = bn[c * 32 + t32];
    }

    // scores (shuffle-reduced per head) + nv kept in acc
    float sc[4][12];
#pragma unroll
    for (int m = 0; m < 12; ++m) {
        const long long ro = (long long)nofs[m] * 128;
#pragma unroll
        for (int c = 0; c < 4; ++c) {
            const int col = c * 32 + t32;
            float tmj = acc[c][m] + bnv[c];
            float nk = kbuf[ro + col] + tmj;
            float nv = vbuf[ro + col] + tmj;
            acc[c][m] = nv;
            float p = qv[c] * nk;
            p += __shfl_xor(p, 1, 16);
            p += __shfl_xor(p, 2, 16);
            p += __shfl_xor(p, 4, 16);
            p += __shfl_xor(p, 8, 16);
            sc[c][m] = p * 0.25f;              // 1/sqrt(D), D=16
        }
    }

    // softmax over M per head + weighted nv sum; att -> q buffer
#pragma unroll
    for (int c = 0; c < 4; ++c) {
        float mx = sc[c][0];
#pragma unroll
        for (int m = 1; m < 12; ++m) mx = fmaxf(mx, sc[c][m]);
        float sum = 0.f, att = 0.f;
#pragma unroll
        for (int m = 0; m < 12; ++m) {
            float e = __expf(sc[c][m] - mx);
            sum += e;
            att += e * acc[c][m];
        }
        qatt[n * 128 + c * 32 + t32] = att / sum;
    }
}

// ---------------------------------------------------------------------------
// K3: out projection + sigmoid gate + residual + LayerNorm.
// 16 atoms/block, 256 threads.
// ---------------------------------------------------------------------------
__global__ __launch_bounds__(256) void out_kernel(
    const float* __restrict__ attb, const float* __restrict__ atom_fea,
    const float* __restrict__ Wo, const float* __restrict__ bo,
    const float* __restrict__ Wg, const float* __restrict__ bg,
    const float* __restrict__ gamma, const float* __restrict__ beta,
    float* __restrict__ out)
{
    __shared__ float s_att[16 * 128];
    __shared__ float s_res[16 * 128];
    __shared__ float s_gate[16];
    __shared__ float s_mu[16], s_rs[16];
    const int tid = threadIdx.x;
    const long long base = (long long)blockIdx.x * (16 * 128);
#pragma unroll
    for (int t = 0; t < 8; ++t) {
        s_att[tid + t * 256] = attb[base + tid + t * 256];
        s_res[tid + t * 256] = atom_fea[base + tid + t * 256];
    }
    __syncthreads();

    const int j = tid & 127;
    const int half = tid >> 7;
    float acc[8];
#pragma unroll
    for (int a = 0; a < 8; ++a) acc[a] = 0.f;

    const float* srow = s_att + half * (8 * 128);
    for (int i = 0; i < 128; i += 4) {
        float wo[4];
#pragma unroll
        for (int ii = 0; ii < 4; ++ii) wo[ii] = Wo[(i + ii) * 128 + j];
#pragma unroll
        for (int a = 0; a < 8; ++a) {
            float4 x = *(const float4*)(srow + a * 128 + i);
            acc[a] += x.x * wo[0] + x.y * wo[1] + x.z * wo[2] + x.w * wo[3];
        }
    }
    const float boj = bo[j];
#pragma unroll
    for (int a = 0; a < 8; ++a) acc[a] += boj;
    __syncthreads();                    // all reads of s_att done
#pragma unroll
    for (int a = 0; a < 8; ++a)
        s_att[(half * 8 + a) * 128 + j] = acc[a];   // s_att := out
    __syncthreads();

    // gate: 16 groups of 16 threads, one atom each
    const int g = tid >> 4;
    const int r = tid & 15;
    float p = 0.f;
#pragma unroll
    for (int tt = 0; tt < 8; ++tt) {
        int jj = r + tt * 16;
        p += s_att[g * 128 + jj] * Wg[jj] + s_res[g * 128 + jj] * Wg[128 + jj];
    }
    p += __shfl_xor(p, 1, 16);
    p += __shfl_xor(p, 2, 16);
    p += __shfl_xor(p, 4, 16);
    p += __shfl_xor(p, 8, 16);
    if (r == 0) s_gate[g] = 1.f / (1.f + __expf(-(p + bg[0])));
    __syncthreads();

    // gated residual -> s_res
#pragma unroll
    for (int a = 0; a < 8; ++a) {
        int aa = half * 8 + a;
        float gt = s_gate[aa];
        float gv = gt * acc[a] + (1.f - gt) * s_res[aa * 128 + j];
        s_res[aa * 128 + j] = gv;
    }
    __syncthreads();

    // LayerNorm stats per atom
    float s1 = 0.f, s2 = 0.f;
#pragma unroll
    for (int tt = 0; tt < 8; ++tt) {
        float x = s_res[g * 128 + r + tt * 16];
        s1 += x; s2 += x * x;
    }
    s1 += __shfl_xor(s1, 1, 16); s2 += __shfl_xor(s2, 1, 16);
    s1 += __shfl_xor(s1, 2, 16); s2 += __shfl_xor(s2, 2, 16);
    s1 += __shfl_xor(s1, 4, 16); s2 += __shfl_xor(s2, 4, 16);
    s1 += __shfl_xor(s1, 8, 16); s2 += __shfl_xor(s2, 8, 16);
    if (r == 0) {
        float mu = s1 * (1.f / 128.f);
        float var = s2 * (1.f / 128.f) - mu * mu;
        s_mu[g] = mu;
        s_rs[g] = rsqrtf(var + 1e-5f);
    }
    __syncthreads();

    const float gmj = gamma[j], btj = beta[j];
#pragma unroll
    for (int a = 0; a < 8; ++a) {
        int aa = half * 8 + a;
        float x = s_res[aa * 128 + j];
        out[base + aa * 128 + j] = (x - s_mu[aa]) * s_rs[aa] * gmj + btj;
    }
}

// ---------------------------------------------------------------------------
extern "C" void kernel_launch(void* const* d_in, const int* in_sizes, int n_in,
                              void* d_out, int out_size, void* d_ws, size_t ws_size,
                              hipStream_t stream) {
    const float* atom_fea = (const float*)d_in[0];
    const float* nbr_fea  = (const float*)d_in[1];
    const int*   nbr_idx  = (const int*)d_in[2];
    const float* Wq = (const float*)d_in[3];
    const float* bq = (const float*)d_in[4];
    const float* Wk = (const float*)d_in[5];
    const float* bk = (const float*)d_in[6];
    const float* Wv = (const float*)d_in[7];
    const float* bv = (const float*)d_in[8];
    const float* Wn = (const float*)d_in[9];
    const float* bn = (const float*)d_in[10];
    const float* Wo = (const float*)d_in[11];
    const float* bo = (const float*)d_in[12];
    const float* Wg = (const float*)d_in[13];
    const float* bg = (const float*)d_in[14];
    const float* gm = (const float*)d_in[15];
    const float* bt = (const float*)d_in[16];

    float* qbuf = (float*)d_ws;                       // [N,128] -> becomes att
    float* kbuf = qbuf + (size_t)NATOM * FDIM;        // [N,128]
    float* vbuf = kbuf + (size_t)NATOM * FDIM;        // [N,128]
    float* outp = (float*)d_out;

    qkv_kernel<<<NATOM / 32, 256, 0, stream>>>(
        atom_fea, Wq, bq, Wk, bk, Wv, bv, qbuf, kbuf, vbuf);
    attn_kernel<<<NATOM / 8, 256, 0, stream>>>(
        nbr_fea, nbr_idx, Wn, bn, qbuf, kbuf, vbuf);
    out_kernel<<<NATOM / 16, 256, 0, stream>>>(
        qbuf, atom_fea, Wo, bo, Wg, bg, gm, bt, outp);
}